// Round 13
// baseline (106.718 us; speedup 1.0000x reference)
//
#include <hip/hip_runtime.h>
#include <hip/hip_bf16.h>

typedef unsigned short u16;
typedef float f32x4 __attribute__((ext_vector_type(4)));
typedef __bf16 bf16x8 __attribute__((ext_vector_type(8)));
typedef u16 u16x8 __attribute__((ext_vector_type(8)));

#define M_DIM 16384
#define IN_DIM 1024
#define OUT_DIM 1024
#define K_KNOTS 12
#define KCAT 2048   // concatenated K dimension

// Fragment-tiled global layout for A and B (R8 layout):
//   X_tiled[(g16*64 + kc)*512 + l*8 + e] = X[g16*16 + (l&15)][kc*32 + (l>>4)*8 + e]
// one wave's global_load_lds (lane*16B) stages one MFMA frag from a
// CONTIGUOUS 1KB global range.

// ---- helpers ----
__device__ __forceinline__ u16 f2bf(float f) {
    unsigned int u = __builtin_bit_cast(unsigned int, f);
    u = u + 0x7FFFu + ((u >> 16) & 1u);   // RNE
    return (u16)(u >> 16);
}

__device__ __forceinline__ void gload_lds16(const void* g, void* l) {
    __builtin_amdgcn_global_load_lds(
        (const __attribute__((address_space(1))) unsigned int*)g,
        (__attribute__((address_space(3))) unsigned int*)l, 16, 0, 0);
}

// ---- kernel 1: per-feature knot prep (sort + sigmoid mask) ----
__global__ void prep_kernel(const float* __restrict__ grid,
                            const float* __restrict__ coeffs,
                            const float* __restrict__ alive,
                            float* __restrict__ pmc,     // [IN][12]
                            float* __restrict__ pgmin,   // [IN]
                            float* __restrict__ pscale)  // [IN]
{
    int i = blockIdx.x * blockDim.x + threadIdx.x;
    if (i >= IN_DIM) return;
    float g[K_KNOTS], c[K_KNOTS], a[K_KNOTS];
    for (int k = 0; k < K_KNOTS; ++k) {
        g[k] = grid[i * K_KNOTS + k];
        c[k] = coeffs[i * K_KNOTS + k];
        a[k] = alive[i * K_KNOTS + k];
    }
    for (int k = 1; k < K_KNOTS; ++k) {
        float gk = g[k], ck = c[k], ak = a[k];
        int j = k - 1;
        while (j >= 0 && g[j] > gk) {
            g[j + 1] = g[j]; c[j + 1] = c[j]; a[j + 1] = a[j]; --j;
        }
        g[j + 1] = gk; c[j + 1] = ck; a[j + 1] = ak;
    }
    for (int k = 0; k < K_KNOTS; ++k)
        pmc[i * K_KNOTS + k] = c[k] / (1.0f + expf(-a[k]));
    pgmin[i] = g[0];
    pscale[i] = (float)(K_KNOTS - 1) / fmaxf(g[K_KNOTS - 1] - g[0], 1e-6f);
}

// ---- kernel 2: pack [proj_w | res_w] into frag-tiled bf16 B ----
__global__ __launch_bounds__(256) void conv_w_kernel(
    const float* __restrict__ pw, const float* __restrict__ rw,
    u16* __restrict__ Bw)
{
    const int n16 = blockIdx.x >> 2;          // 0..63
    const int jb  = (blockIdx.x & 3) * 4;     // 0,4,8,12
    const int tid = threadIdx.x;
    #pragma unroll 1
    for (int j = jb; j < jb + 4; ++j) {
        int s = j * 256 + tid;        // 0..4095
        int kc = s >> 6, l = s & 63;
        int row = n16 * 16 + (l & 15);
        int k = kc * 32 + ((l >> 4) & 3) * 8;
        const float* src = (k < IN_DIM) ? &pw[(long)row * IN_DIM + k]
                                        : &rw[(long)row * IN_DIM + (k - IN_DIM)];
        float4 v0 = *(const float4*)src;
        float4 v1 = *(const float4*)(src + 4);
        u16x8 ov;
        ov[0] = f2bf(v0.x); ov[1] = f2bf(v0.y); ov[2] = f2bf(v0.z); ov[3] = f2bf(v0.w);
        ov[4] = f2bf(v1.x); ov[5] = f2bf(v1.y); ov[6] = f2bf(v1.z); ov[7] = f2bf(v1.w);
        *(u16x8*)&Bw[((long)n16 * 64 + kc) * 512 + l * 8] = ov;
    }
}

// ---- kernel 3: build A = [spline(x) | x] frag-tiled, 16 rows/block ----
// 1024 blocks x 512 threads, LDS = xt only (16.6 KB) -> 4 blocks/CU
// (32 waves/CU). Params gathered from L1/L2 directly (read-only, 56 KB).
#define XT_STR 260   // 256 + 4 pad floats

__global__ __launch_bounds__(512) void build_a_kernel(
    const float* __restrict__ x,
    const float* __restrict__ pmc,
    const float* __restrict__ pgmin,
    const float* __restrict__ pscale,
    u16* __restrict__ Abf)
{
    __shared__ float xt[16 * XT_STR];
    const int tid = threadIdx.x;
    const int m16 = blockIdx.x;   // 0..1023

    #pragma unroll 1
    for (int c0 = 0; c0 < IN_DIM; c0 += 256) {
        if (c0) __syncthreads();   // WAR on xt (uniform branch)

        // phase A: coalesced x load -> xt (16 rows x 256 cols)
        #pragma unroll
        for (int p = 0; p < 2; ++p) {
            int idx = p * 512 + tid;
            int r = idx >> 6, lc = (idx & 63) * 4;
            *(float4*)&xt[r * XT_STR + lc] =
                *(const float4*)&x[(long)(m16 * 16 + r) * IN_DIM + c0 + lc];
        }
        __syncthreads();

        // phase B: frag-ordered LDS reads, param gather from L1, spline+copy
        {
            int kc_l = tid >> 6, l = tid & 63;
            int r = l & 15;
            int cb = kc_l * 32 + ((l >> 4) & 3) * 8;
            const float* xp = &xt[r * XT_STR + cb];
            float4 v0 = *(const float4*)xp;
            float4 v1 = *(const float4*)(xp + 4);
            float xs[8] = {v0.x, v0.y, v0.z, v0.w, v1.x, v1.y, v1.z, v1.w};

            // aligned 16B param loads (cb is a multiple of 8)
            float4 g0 = *(const float4*)&pgmin[c0 + cb];
            float4 g1 = *(const float4*)&pgmin[c0 + cb + 4];
            float4 s0 = *(const float4*)&pscale[c0 + cb];
            float4 s1 = *(const float4*)&pscale[c0 + cb + 4];
            float gm[8] = {g0.x, g0.y, g0.z, g0.w, g1.x, g1.y, g1.z, g1.w};
            float sc[8] = {s0.x, s0.y, s0.z, s0.w, s1.x, s1.y, s1.z, s1.w};

            u16x8 so, co;
            #pragma unroll
            for (int e = 0; e < 8; ++e) {
                int i = c0 + cb + e;
                float xx = xs[e];
                float xn = (xx - gm[e]) * sc[e];
                xn = fminf(fmaxf(xn, 0.0f), (float)(K_KNOTS - 1));
                int li = (int)xn;
                if (li > K_KNOTS - 2) li = K_KNOTS - 2;
                float frac = xn - (float)li;
                float cl = pmc[i * K_KNOTS + li];       // L1-resident gather
                float cr = pmc[i * K_KNOTS + li + 1];
                so[e] = f2bf(cl + frac * (cr - cl));
                co[e] = f2bf(xx);
            }
            long kcS = (long)m16 * 64 + (c0 >> 5) + kc_l;   // spline half
            *(u16x8*)&Abf[kcS * 512 + l * 8] = so;
            *(u16x8*)&Abf[(kcS + 32) * 512 + l * 8] = co;   // copy half
        }
    }
}

// ---- kernel 4: 128x256 bf16 GEMM, TBK=32, 2 blocks/CU (R8, best known) ----
// 8 waves (2M x 4N, per-wave 64x64), 48 KiB double-buffered LDS, one phase
// per K-tile: {8 ds_read -> lgkm0 -> 16 MFMA -> bar -> stage T+2 -> vmcnt(3)+bar}.
#define TBK 32
#define NT (KCAT / TBK)   // 64 K-tiles
#define MSTR 32768L       // m16/n16-group stride in frag-tiled layout

#define BAR()     asm volatile("s_barrier" ::: "memory")
#define VM3BAR()  asm volatile("s_waitcnt vmcnt(3)\ns_barrier" ::: "memory")
#define LGKM0()   do { asm volatile("s_waitcnt lgkmcnt(0)" ::: "memory"); \
                       __builtin_amdgcn_sched_barrier(0); } while (0)

// LDS map (u16): A buf b @ b*4096 (8 frags x 512); B buf b @ 8192 + b*8192
// (16 frags x 512). Total 24576 u16 = 48 KiB. Lane-order frags (conflict-free).
#define STAGE2(T, cb) do { \
    gload_lds16(pAf +          ((long)(T)) * 512, &lds[(cb) * 4096 + tid * 8]); \
    gload_lds16(pBf +          ((long)(T)) * 512, &lds[8192 + (cb) * 8192 + tid * 8]); \
    gload_lds16(pBf + 8*MSTR + ((long)(T)) * 512, &lds[8192 + (cb) * 8192 + 4096 + tid * 8]); } while (0)

__global__ __launch_bounds__(512, 4) void gemm_kernel(
    const u16* __restrict__ A,   // frag-tiled, 1024 m16-groups
    const u16* __restrict__ B,   // frag-tiled, 64 n16-groups
    const float* __restrict__ bias,
    float* __restrict__ C)
{
    __shared__ __align__(16) u16 lds[24576];   // 48 KiB

    const int tid  = threadIdx.x;
    const int lane = tid & 63;
    const int wave = tid >> 6;
    const int wm   = wave >> 2;   // 0..1
    const int wn   = wave & 3;    // 0..3

    // bijective XCD swizzle (nwg = 512, divisible by 8)
    int wgid = (blockIdx.x & 7) * 64 + (blockIdx.x >> 3);
    const int brow = (wgid >> 2) * 128;
    const int bcol = (wgid & 3) * 256;

    // contiguous staging sources: wave w stages A frag w, B frags w and w+8
    const u16* pAf = A + ((long)(brow >> 4) + wave) * MSTR + lane * 8;
    const u16* pBf = B + ((long)(bcol >> 4) + wave) * MSTR + lane * 8;

    const int loff = lane * 8;    // lane-order frag read

    f32x4 acc[4][4] = {};
    bf16x8 af[4], bfr[4];

    // prologue: tile 0 -> buf0, tile 1 -> buf1 (3 gloads/wave each)
    STAGE2(0, 0);
    STAGE2(1, 1);
    VM3BAR();   // tile 0 complete; tile 1's 3 ops may remain in flight

    #pragma unroll 1
    for (int t = 0; t < NT; ++t) {
        const int cb = t & 1;
        const int ab = cb * 4096;
        const int bb = 8192 + cb * 8192;

        #pragma unroll
        for (int m_ = 0; m_ < 4; ++m_)
            af[m_] = *(const bf16x8*)&lds[ab + (wm * 4 + m_) * 512 + loff];
        #pragma unroll
        for (int n_ = 0; n_ < 4; ++n_)
            bfr[n_] = *(const bf16x8*)&lds[bb + (wn * 4 + n_) * 512 + loff];
        LGKM0();
        __builtin_amdgcn_s_setprio(1);
        #pragma unroll
        for (int m_ = 0; m_ < 4; ++m_)
            #pragma unroll
            for (int n_ = 0; n_ < 4; ++n_)
                acc[m_][n_] = __builtin_amdgcn_mfma_f32_16x16x32_bf16(
                    af[m_], bfr[n_], acc[m_][n_], 0, 0, 0);
        __builtin_amdgcn_s_setprio(0);
        BAR();                       // all waves done reading buf cb

        const int T2 = (t + 2) & 63; // wrap: staged, never read; in-bounds
        STAGE2(T2, cb);
        VM3BAR();                    // tile t+1 (other buf) complete for all waves
    }

    // ---- epilogue ----
    const int crow0 = brow + wm * 64 + (lane >> 4) * 4;
    const int ccol0 = bcol + wn * 64 + (lane & 15);
    float bv[4];
    #pragma unroll
    for (int n = 0; n < 4; ++n) bv[n] = bias[ccol0 + n * 16];
    #pragma unroll
    for (int m = 0; m < 4; ++m) {
        #pragma unroll
        for (int n = 0; n < 4; ++n) {
            #pragma unroll
            for (int j = 0; j < 4; ++j) {
                int row = crow0 + m * 16 + j;
                C[(long)row * OUT_DIM + ccol0 + n * 16] = acc[m][n][j] + bv[n];
            }
        }
    }
}

extern "C" void kernel_launch(void* const* d_in, const int* in_sizes, int n_in,
                              void* d_out, int out_size, void* d_ws, size_t ws_size,
                              hipStream_t stream) {
    const float* x      = (const float*)d_in[0];
    const float* grid   = (const float*)d_in[1];
    const float* coeffs = (const float*)d_in[2];
    const float* alive  = (const float*)d_in[3];
    const float* proj_w = (const float*)d_in[4];
    const float* proj_b = (const float*)d_in[5];
    const float* res_w  = (const float*)d_in[6];
    float* out = (float*)d_out;

    char* w = (char*)d_ws;
    size_t a_bytes = (size_t)M_DIM * KCAT * sizeof(u16);     // 64 MiB
    size_t b_bytes = (size_t)OUT_DIM * KCAT * sizeof(u16);   // 4 MiB
    u16* Abf   = (u16*)w;
    u16* Bw    = (u16*)(w + a_bytes);
    float* pmc = (float*)(w + a_bytes + b_bytes);
    float* pgmin  = pmc + IN_DIM * K_KNOTS;
    float* pscale = pgmin + IN_DIM;

    prep_kernel<<<(IN_DIM + 255) / 256, 256, 0, stream>>>(grid, coeffs, alive,
                                                          pmc, pgmin, pscale);
    conv_w_kernel<<<(OUT_DIM / 16) * 4, 256, 0, stream>>>(proj_w, res_w, Bw);
    build_a_kernel<<<M_DIM / 16, 512, 0, stream>>>(x, pmc, pgmin, pscale, Abf);
    gemm_kernel<<<(M_DIM / 128) * (OUT_DIM / 256), 512, 0, stream>>>(Abf, Bw, proj_b, out);
}

// Round 14
// 95.200 us; speedup vs baseline: 1.1210x; 1.1210x over previous
//
#include <hip/hip_runtime.h>
#include <hip/hip_bf16.h>

typedef unsigned short u16;
typedef float f32x4 __attribute__((ext_vector_type(4)));
typedef __bf16 bf16x8 __attribute__((ext_vector_type(8)));
typedef u16 u16x8 __attribute__((ext_vector_type(8)));

#define M_DIM 16384
#define IN_DIM 1024
#define OUT_DIM 1024
#define K_KNOTS 12
#define KCAT 2048   // concatenated K dimension

// Fragment-tiled global layout for A and B (R8/R12 layout):
//   X_tiled[(g16*64 + kc)*512 + l*8 + e] = X[g16*16 + (l&15)][kc*32 + (l>>4)*8 + e]
// one wave's global_load_lds (lane*16B) stages one MFMA frag from a
// CONTIGUOUS 1KB global range.

// ---- helpers ----
__device__ __forceinline__ u16 f2bf(float f) {
    unsigned int u = __builtin_bit_cast(unsigned int, f);
    u = u + 0x7FFFu + ((u >> 16) & 1u);   // RNE
    return (u16)(u >> 16);
}

__device__ __forceinline__ void gload_lds16(const void* g, void* l) {
    __builtin_amdgcn_global_load_lds(
        (const __attribute__((address_space(1))) unsigned int*)g,
        (__attribute__((address_space(3))) unsigned int*)l, 16, 0, 0);
}

// ---- kernel 1: MERGED prep (blocks 256..259) + conv_w (blocks 0..255) ----
__global__ __launch_bounds__(256) void prep_conv_kernel(
    const float* __restrict__ grid,
    const float* __restrict__ coeffs,
    const float* __restrict__ alive,
    const float* __restrict__ pw,
    const float* __restrict__ rw,
    float* __restrict__ pmc,     // [IN][12]
    float* __restrict__ pgmin,   // [IN]
    float* __restrict__ pscale,  // [IN]
    u16* __restrict__ Bw)
{
    const int tid = threadIdx.x;
    if (blockIdx.x < 256) {
        // ---- conv_w: pack [proj_w | res_w] into frag-tiled bf16 B ----
        const int n16 = blockIdx.x >> 2;          // 0..63
        const int jb  = (blockIdx.x & 3) * 4;     // 0,4,8,12
        #pragma unroll 1
        for (int j = jb; j < jb + 4; ++j) {
            int s = j * 256 + tid;        // 0..4095
            int kc = s >> 6, l = s & 63;
            int row = n16 * 16 + (l & 15);
            int k = kc * 32 + ((l >> 4) & 3) * 8;
            const float* src = (k < IN_DIM) ? &pw[(long)row * IN_DIM + k]
                                            : &rw[(long)row * IN_DIM + (k - IN_DIM)];
            float4 v0 = *(const float4*)src;
            float4 v1 = *(const float4*)(src + 4);
            u16x8 ov;
            ov[0] = f2bf(v0.x); ov[1] = f2bf(v0.y); ov[2] = f2bf(v0.z); ov[3] = f2bf(v0.w);
            ov[4] = f2bf(v1.x); ov[5] = f2bf(v1.y); ov[6] = f2bf(v1.z); ov[7] = f2bf(v1.w);
            *(u16x8*)&Bw[((long)n16 * 64 + kc) * 512 + l * 8] = ov;
        }
    } else {
        // ---- prep: per-feature knot sort + sigmoid mask ----
        int i = (blockIdx.x - 256) * 256 + tid;
        if (i >= IN_DIM) return;
        float g[K_KNOTS], c[K_KNOTS], a[K_KNOTS];
        for (int k = 0; k < K_KNOTS; ++k) {
            g[k] = grid[i * K_KNOTS + k];
            c[k] = coeffs[i * K_KNOTS + k];
            a[k] = alive[i * K_KNOTS + k];
        }
        for (int k = 1; k < K_KNOTS; ++k) {
            float gk = g[k], ck = c[k], ak = a[k];
            int j = k - 1;
            while (j >= 0 && g[j] > gk) {
                g[j + 1] = g[j]; c[j + 1] = c[j]; a[j + 1] = a[j]; --j;
            }
            g[j + 1] = gk; c[j + 1] = ck; a[j + 1] = ak;
        }
        for (int k = 0; k < K_KNOTS; ++k)
            pmc[i * K_KNOTS + k] = c[k] / (1.0f + expf(-a[k]));
        pgmin[i] = g[0];
        pscale[i] = (float)(K_KNOTS - 1) / fmaxf(g[K_KNOTS - 1] - g[0], 1e-6f);
    }
}

// ---- kernel 2: build A = [spline(x) | x] frag-tiled, 32 rows/block (R12) ----
// 512 blocks x 512 threads, 73 KB LDS -> 2 blocks/CU (16 waves/CU).
#define XT_STR 260   // 256 + 4 pad floats

__global__ __launch_bounds__(512) void build_a_kernel(
    const float* __restrict__ x,
    const float* __restrict__ pmc,
    const float* __restrict__ pgmin,
    const float* __restrict__ pscale,
    u16* __restrict__ Abf)
{
    __shared__ float s_mc[IN_DIM * K_KNOTS];
    __shared__ float s_gmin[IN_DIM];
    __shared__ float s_scale[IN_DIM];
    __shared__ float xt[16 * XT_STR];
    const int tid = threadIdx.x;
    for (int i = tid; i < IN_DIM * K_KNOTS; i += 512) s_mc[i] = pmc[i];
    for (int i = tid; i < IN_DIM; i += 512) { s_gmin[i] = pgmin[i]; s_scale[i] = pscale[i]; }

    #pragma unroll 1
    for (int g = 0; g < 2; ++g) {
        const int m16 = blockIdx.x * 2 + g;
        #pragma unroll 1
        for (int c0 = 0; c0 < IN_DIM; c0 += 256) {
            __syncthreads();   // params ready (first iter); WAR on xt (rest)

            // phase A: coalesced x load -> xt (16 rows x 256 cols)
            #pragma unroll
            for (int p = 0; p < 2; ++p) {
                int idx = p * 512 + tid;
                int r = idx >> 6, lc = (idx & 63) * 4;
                float4 v = *(const float4*)&x[(long)(m16 * 16 + r) * IN_DIM + c0 + lc];
                *(float4*)&xt[r * XT_STR + lc] = v;
            }
            __syncthreads();

            // phase B: frag-ordered LDS reads, spline + copy, coalesced stores
            {
                int kc_l = tid >> 6, l = tid & 63;
                int r = l & 15;
                int cb = kc_l * 32 + ((l >> 4) & 3) * 8;
                const float* xp = &xt[r * XT_STR + cb];
                float4 v0 = *(const float4*)xp;
                float4 v1 = *(const float4*)(xp + 4);
                float xs[8] = {v0.x, v0.y, v0.z, v0.w, v1.x, v1.y, v1.z, v1.w};
                u16x8 so, co;
                #pragma unroll
                for (int e = 0; e < 8; ++e) {
                    int i = c0 + cb + e;
                    float xx = xs[e];
                    float xn = (xx - s_gmin[i]) * s_scale[i];
                    xn = fminf(fmaxf(xn, 0.0f), (float)(K_KNOTS - 1));
                    int li = (int)xn;
                    if (li > K_KNOTS - 2) li = K_KNOTS - 2;
                    float frac = xn - (float)li;
                    float cl = s_mc[i * K_KNOTS + li];
                    float cr = s_mc[i * K_KNOTS + li + 1];
                    so[e] = f2bf(cl + frac * (cr - cl));
                    co[e] = f2bf(xx);
                }
                long kcS = (long)m16 * 64 + (c0 >> 5) + kc_l;   // spline half
                *(u16x8*)&Abf[kcS * 512 + l * 8] = so;
                *(u16x8*)&Abf[(kcS + 32) * 512 + l * 8] = co;   // copy half
            }
        }
    }
}

// ---- kernel 3: 128x256 bf16 GEMM, TBK=32, 2 blocks/CU (R8, best known) ----
// 8 waves (2M x 4N, per-wave 64x64), 48 KiB double-buffered LDS, one phase
// per K-tile: {8 ds_read -> lgkm0 -> 16 MFMA -> bar -> stage T+2 -> vmcnt(3)+bar}.
#define TBK 32
#define NT (KCAT / TBK)   // 64 K-tiles
#define MSTR 32768L       // m16/n16-group stride in frag-tiled layout

#define BAR()     asm volatile("s_barrier" ::: "memory")
#define VM3BAR()  asm volatile("s_waitcnt vmcnt(3)\ns_barrier" ::: "memory")
#define LGKM0()   do { asm volatile("s_waitcnt lgkmcnt(0)" ::: "memory"); \
                       __builtin_amdgcn_sched_barrier(0); } while (0)

// LDS map (u16): A buf b @ b*4096 (8 frags x 512); B buf b @ 8192 + b*8192
// (16 frags x 512). Total 24576 u16 = 48 KiB. Lane-order frags (conflict-free).
#define STAGE2(T, cb) do { \
    gload_lds16(pAf +          ((long)(T)) * 512, &lds[(cb) * 4096 + tid * 8]); \
    gload_lds16(pBf +          ((long)(T)) * 512, &lds[8192 + (cb) * 8192 + tid * 8]); \
    gload_lds16(pBf + 8*MSTR + ((long)(T)) * 512, &lds[8192 + (cb) * 8192 + 4096 + tid * 8]); } while (0)

__global__ __launch_bounds__(512, 4) void gemm_kernel(
    const u16* __restrict__ A,   // frag-tiled, 1024 m16-groups
    const u16* __restrict__ B,   // frag-tiled, 64 n16-groups
    const float* __restrict__ bias,
    float* __restrict__ C)
{
    __shared__ __align__(16) u16 lds[24576];   // 48 KiB

    const int tid  = threadIdx.x;
    const int lane = tid & 63;
    const int wave = tid >> 6;
    const int wm   = wave >> 2;   // 0..1
    const int wn   = wave & 3;    // 0..3

    // bijective XCD swizzle (nwg = 512, divisible by 8)
    int wgid = (blockIdx.x & 7) * 64 + (blockIdx.x >> 3);
    const int brow = (wgid >> 2) * 128;
    const int bcol = (wgid & 3) * 256;

    // contiguous staging sources: wave w stages A frag w, B frags w and w+8
    const u16* pAf = A + ((long)(brow >> 4) + wave) * MSTR + lane * 8;
    const u16* pBf = B + ((long)(bcol >> 4) + wave) * MSTR + lane * 8;

    const int loff = lane * 8;    // lane-order frag read

    f32x4 acc[4][4] = {};
    bf16x8 af[4], bfr[4];

    // prologue: tile 0 -> buf0, tile 1 -> buf1 (3 gloads/wave each)
    STAGE2(0, 0);
    STAGE2(1, 1);
    VM3BAR();   // tile 0 complete; tile 1's 3 ops may remain in flight

    #pragma unroll 1
    for (int t = 0; t < NT; ++t) {
        const int cb = t & 1;
        const int ab = cb * 4096;
        const int bb = 8192 + cb * 8192;

        #pragma unroll
        for (int m_ = 0; m_ < 4; ++m_)
            af[m_] = *(const bf16x8*)&lds[ab + (wm * 4 + m_) * 512 + loff];
        #pragma unroll
        for (int n_ = 0; n_ < 4; ++n_)
            bfr[n_] = *(const bf16x8*)&lds[bb + (wn * 4 + n_) * 512 + loff];
        LGKM0();
        __builtin_amdgcn_s_setprio(1);
        #pragma unroll
        for (int m_ = 0; m_ < 4; ++m_)
            #pragma unroll
            for (int n_ = 0; n_ < 4; ++n_)
                acc[m_][n_] = __builtin_amdgcn_mfma_f32_16x16x32_bf16(
                    af[m_], bfr[n_], acc[m_][n_], 0, 0, 0);
        __builtin_amdgcn_s_setprio(0);
        BAR();                       // all waves done reading buf cb

        const int T2 = (t + 2) & 63; // wrap: staged, never read; in-bounds
        STAGE2(T2, cb);
        VM3BAR();                    // tile t+1 (other buf) complete for all waves
    }

    // ---- epilogue ----
    const int crow0 = brow + wm * 64 + (lane >> 4) * 4;
    const int ccol0 = bcol + wn * 64 + (lane & 15);
    float bv[4];
    #pragma unroll
    for (int n = 0; n < 4; ++n) bv[n] = bias[ccol0 + n * 16];
    #pragma unroll
    for (int m = 0; m < 4; ++m) {
        #pragma unroll
        for (int n = 0; n < 4; ++n) {
            #pragma unroll
            for (int j = 0; j < 4; ++j) {
                int row = crow0 + m * 16 + j;
                C[(long)row * OUT_DIM + ccol0 + n * 16] = acc[m][n][j] + bv[n];
            }
        }
    }
}

extern "C" void kernel_launch(void* const* d_in, const int* in_sizes, int n_in,
                              void* d_out, int out_size, void* d_ws, size_t ws_size,
                              hipStream_t stream) {
    const float* x      = (const float*)d_in[0];
    const float* grid   = (const float*)d_in[1];
    const float* coeffs = (const float*)d_in[2];
    const float* alive  = (const float*)d_in[3];
    const float* proj_w = (const float*)d_in[4];
    const float* proj_b = (const float*)d_in[5];
    const float* res_w  = (const float*)d_in[6];
    float* out = (float*)d_out;

    char* w = (char*)d_ws;
    size_t a_bytes = (size_t)M_DIM * KCAT * sizeof(u16);     // 64 MiB
    size_t b_bytes = (size_t)OUT_DIM * KCAT * sizeof(u16);   // 4 MiB
    u16* Abf   = (u16*)w;
    u16* Bw    = (u16*)(w + a_bytes);
    float* pmc = (float*)(w + a_bytes + b_bytes);
    float* pgmin  = pmc + IN_DIM * K_KNOTS;
    float* pscale = pgmin + IN_DIM;

    prep_conv_kernel<<<260, 256, 0, stream>>>(grid, coeffs, alive, proj_w, res_w,
                                              pmc, pgmin, pscale, Bw);
    build_a_kernel<<<M_DIM / 32, 512, 0, stream>>>(x, pmc, pgmin, pscale, Abf);
    gemm_kernel<<<(M_DIM / 128) * (OUT_DIM / 256), 512, 0, stream>>>(Abf, Bw, proj_b, out);
}

// Round 15
// 95.134 us; speedup vs baseline: 1.1218x; 1.0007x over previous
//
#include <hip/hip_runtime.h>
#include <hip/hip_bf16.h>

typedef unsigned short u16;
typedef float f32x4 __attribute__((ext_vector_type(4)));
typedef __bf16 bf16x8 __attribute__((ext_vector_type(8)));
typedef u16 u16x8 __attribute__((ext_vector_type(8)));

#define M_DIM 16384
#define IN_DIM 1024
#define OUT_DIM 1024
#define K_KNOTS 12
#define KCAT 2048   // concatenated K dimension

// Fragment-tiled global layout for A and B (R8/R12 layout):
//   X_tiled[(g16*64 + kc)*512 + l*8 + e] = X[g16*16 + (l&15)][kc*32 + (l>>4)*8 + e]
// one wave's global_load_lds (lane*16B) stages one MFMA frag from a
// CONTIGUOUS 1KB global range.

// ---- helpers ----
__device__ __forceinline__ u16 f2bf(float f) {
    unsigned int u = __builtin_bit_cast(unsigned int, f);
    u = u + 0x7FFFu + ((u >> 16) & 1u);   // RNE
    return (u16)(u >> 16);
}

__device__ __forceinline__ void gload_lds16(const void* g, void* l) {
    __builtin_amdgcn_global_load_lds(
        (const __attribute__((address_space(1))) unsigned int*)g,
        (__attribute__((address_space(3))) unsigned int*)l, 16, 0, 0);
}

// ---- kernel 1: MERGED prep (blocks 256..259) + conv_w (blocks 0..255) ----
__global__ __launch_bounds__(256) void prep_conv_kernel(
    const float* __restrict__ grid,
    const float* __restrict__ coeffs,
    const float* __restrict__ alive,
    const float* __restrict__ pw,
    const float* __restrict__ rw,
    float* __restrict__ pmc,     // [IN][12]
    float* __restrict__ pgmin,   // [IN]
    float* __restrict__ pscale,  // [IN]
    u16* __restrict__ Bw)
{
    const int tid = threadIdx.x;
    if (blockIdx.x < 256) {
        // ---- conv_w: pack [proj_w | res_w] into frag-tiled bf16 B ----
        const int n16 = blockIdx.x >> 2;          // 0..63
        const int jb  = (blockIdx.x & 3) * 4;     // 0,4,8,12
        #pragma unroll 1
        for (int j = jb; j < jb + 4; ++j) {
            int s = j * 256 + tid;        // 0..4095
            int kc = s >> 6, l = s & 63;
            int row = n16 * 16 + (l & 15);
            int k = kc * 32 + ((l >> 4) & 3) * 8;
            const float* src = (k < IN_DIM) ? &pw[(long)row * IN_DIM + k]
                                            : &rw[(long)row * IN_DIM + (k - IN_DIM)];
            float4 v0 = *(const float4*)src;
            float4 v1 = *(const float4*)(src + 4);
            u16x8 ov;
            ov[0] = f2bf(v0.x); ov[1] = f2bf(v0.y); ov[2] = f2bf(v0.z); ov[3] = f2bf(v0.w);
            ov[4] = f2bf(v1.x); ov[5] = f2bf(v1.y); ov[6] = f2bf(v1.z); ov[7] = f2bf(v1.w);
            *(u16x8*)&Bw[((long)n16 * 64 + kc) * 512 + l * 8] = ov;
        }
    } else {
        // ---- prep: per-feature knot sort + sigmoid mask ----
        int i = (blockIdx.x - 256) * 256 + tid;
        if (i >= IN_DIM) return;
        float g[K_KNOTS], c[K_KNOTS], a[K_KNOTS];
        for (int k = 0; k < K_KNOTS; ++k) {
            g[k] = grid[i * K_KNOTS + k];
            c[k] = coeffs[i * K_KNOTS + k];
            a[k] = alive[i * K_KNOTS + k];
        }
        for (int k = 1; k < K_KNOTS; ++k) {
            float gk = g[k], ck = c[k], ak = a[k];
            int j = k - 1;
            while (j >= 0 && g[j] > gk) {
                g[j + 1] = g[j]; c[j + 1] = c[j]; a[j + 1] = a[j]; --j;
            }
            g[j + 1] = gk; c[j + 1] = ck; a[j + 1] = ak;
        }
        for (int k = 0; k < K_KNOTS; ++k)
            pmc[i * K_KNOTS + k] = c[k] / (1.0f + expf(-a[k]));
        pgmin[i] = g[0];
        pscale[i] = (float)(K_KNOTS - 1) / fmaxf(g[K_KNOTS - 1] - g[0], 1e-6f);
    }
}

// ---- kernel 2: build A = [spline(x) | x] frag-tiled, col-sliced ----
// 1024 blocks x 512 threads: block = 64-row panel x 256-col slice.
// Per-block params = 256 features (14 KB LDS) + xt tile (16.6 KB) = ~31 KB
// -> 4 blocks/CU resident (32 waves/CU), double R12's residency.
#define XT_STR 260   // 256 + 4 pad floats

__global__ __launch_bounds__(512) void build_a_kernel(
    const float* __restrict__ x,
    const float* __restrict__ pmc,
    const float* __restrict__ pgmin,
    const float* __restrict__ pscale,
    u16* __restrict__ Abf)
{
    __shared__ float s_mc[256 * K_KNOTS];   // 12 KB (col-slice coeffs)
    __shared__ float s_gmin[256];
    __shared__ float s_scale[256];
    __shared__ float xt[16 * XT_STR];       // 16.6 KB transpose tile
    const int tid = threadIdx.x;
    const int mp = blockIdx.x >> 2;         // row panel 0..255 (64 rows)
    const int c0 = (blockIdx.x & 3) * 256;  // col slice base

    // load this slice's params (contiguous: pmc[c0*12 ..])
    for (int i = tid; i < 256 * K_KNOTS; i += 512) s_mc[i] = pmc[c0 * K_KNOTS + i];
    if (tid < 256) { s_gmin[tid] = pgmin[c0 + tid]; s_scale[tid] = pscale[c0 + tid]; }

    #pragma unroll 1
    for (int g = 0; g < 4; ++g) {
        const int m16 = mp * 4 + g;
        __syncthreads();   // params ready (g=0); WAR on xt (g>0)

        // phase A: coalesced x load -> xt (16 rows x 256 cols of the slice)
        #pragma unroll
        for (int p = 0; p < 2; ++p) {
            int idx = p * 512 + tid;
            int r = idx >> 6, lc = (idx & 63) * 4;
            *(float4*)&xt[r * XT_STR + lc] =
                *(const float4*)&x[(long)(m16 * 16 + r) * IN_DIM + c0 + lc];
        }
        __syncthreads();

        // phase B: frag-ordered LDS reads, spline + copy, coalesced stores
        {
            int kc_l = tid >> 6, l = tid & 63;
            int r = l & 15;
            int cb = kc_l * 32 + ((l >> 4) & 3) * 8;   // local col 0..255
            const float* xp = &xt[r * XT_STR + cb];
            float4 v0 = *(const float4*)xp;
            float4 v1 = *(const float4*)(xp + 4);
            float xs[8] = {v0.x, v0.y, v0.z, v0.w, v1.x, v1.y, v1.z, v1.w};
            u16x8 so, co;
            #pragma unroll
            for (int e = 0; e < 8; ++e) {
                int il = cb + e;                       // local feature index
                float xx = xs[e];
                float xn = (xx - s_gmin[il]) * s_scale[il];
                xn = fminf(fmaxf(xn, 0.0f), (float)(K_KNOTS - 1));
                int li = (int)xn;
                if (li > K_KNOTS - 2) li = K_KNOTS - 2;
                float frac = xn - (float)li;
                float cl = s_mc[il * K_KNOTS + li];
                float cr = s_mc[il * K_KNOTS + li + 1];
                so[e] = f2bf(cl + frac * (cr - cl));
                co[e] = f2bf(xx);
            }
            long kcS = (long)m16 * 64 + (c0 >> 5) + kc_l;   // spline half
            *(u16x8*)&Abf[kcS * 512 + l * 8] = so;
            *(u16x8*)&Abf[(kcS + 32) * 512 + l * 8] = co;   // copy half
        }
    }
}

// ---- kernel 3: 128x256 bf16 GEMM, TBK=32, 2 blocks/CU (R8, best known) ----
// 8 waves (2M x 4N, per-wave 64x64), 48 KiB double-buffered LDS, one phase
// per K-tile: {8 ds_read -> lgkm0 -> 16 MFMA -> bar -> stage T+2 -> vmcnt(3)+bar}.
#define TBK 32
#define NT (KCAT / TBK)   // 64 K-tiles
#define MSTR 32768L       // m16/n16-group stride in frag-tiled layout

#define BAR()     asm volatile("s_barrier" ::: "memory")
#define VM3BAR()  asm volatile("s_waitcnt vmcnt(3)\ns_barrier" ::: "memory")
#define LGKM0()   do { asm volatile("s_waitcnt lgkmcnt(0)" ::: "memory"); \
                       __builtin_amdgcn_sched_barrier(0); } while (0)

// LDS map (u16): A buf b @ b*4096 (8 frags x 512); B buf b @ 8192 + b*8192
// (16 frags x 512). Total 24576 u16 = 48 KiB. Lane-order frags (conflict-free).
#define STAGE2(T, cb) do { \
    gload_lds16(pAf +          ((long)(T)) * 512, &lds[(cb) * 4096 + tid * 8]); \
    gload_lds16(pBf +          ((long)(T)) * 512, &lds[8192 + (cb) * 8192 + tid * 8]); \
    gload_lds16(pBf + 8*MSTR + ((long)(T)) * 512, &lds[8192 + (cb) * 8192 + 4096 + tid * 8]); } while (0)

__global__ __launch_bounds__(512, 4) void gemm_kernel(
    const u16* __restrict__ A,   // frag-tiled, 1024 m16-groups
    const u16* __restrict__ B,   // frag-tiled, 64 n16-groups
    const float* __restrict__ bias,
    float* __restrict__ C)
{
    __shared__ __align__(16) u16 lds[24576];   // 48 KiB

    const int tid  = threadIdx.x;
    const int lane = tid & 63;
    const int wave = tid >> 6;
    const int wm   = wave >> 2;   // 0..1
    const int wn   = wave & 3;    // 0..3

    // bijective XCD swizzle (nwg = 512, divisible by 8)
    int wgid = (blockIdx.x & 7) * 64 + (blockIdx.x >> 3);
    const int brow = (wgid >> 2) * 128;
    const int bcol = (wgid & 3) * 256;

    // contiguous staging sources: wave w stages A frag w, B frags w and w+8
    const u16* pAf = A + ((long)(brow >> 4) + wave) * MSTR + lane * 8;
    const u16* pBf = B + ((long)(bcol >> 4) + wave) * MSTR + lane * 8;

    const int loff = lane * 8;    // lane-order frag read

    f32x4 acc[4][4] = {};
    bf16x8 af[4], bfr[4];

    // prologue: tile 0 -> buf0, tile 1 -> buf1 (3 gloads/wave each)
    STAGE2(0, 0);
    STAGE2(1, 1);
    VM3BAR();   // tile 0 complete; tile 1's 3 ops may remain in flight

    #pragma unroll 1
    for (int t = 0; t < NT; ++t) {
        const int cb = t & 1;
        const int ab = cb * 4096;
        const int bb = 8192 + cb * 8192;

        #pragma unroll
        for (int m_ = 0; m_ < 4; ++m_)
            af[m_] = *(const bf16x8*)&lds[ab + (wm * 4 + m_) * 512 + loff];
        #pragma unroll
        for (int n_ = 0; n_ < 4; ++n_)
            bfr[n_] = *(const bf16x8*)&lds[bb + (wn * 4 + n_) * 512 + loff];
        LGKM0();
        __builtin_amdgcn_s_setprio(1);
        #pragma unroll
        for (int m_ = 0; m_ < 4; ++m_)
            #pragma unroll
            for (int n_ = 0; n_ < 4; ++n_)
                acc[m_][n_] = __builtin_amdgcn_mfma_f32_16x16x32_bf16(
                    af[m_], bfr[n_], acc[m_][n_], 0, 0, 0);
        __builtin_amdgcn_s_setprio(0);
        BAR();                       // all waves done reading buf cb

        const int T2 = (t + 2) & 63; // wrap: staged, never read; in-bounds
        STAGE2(T2, cb);
        VM3BAR();                    // tile t+1 (other buf) complete for all waves
    }

    // ---- epilogue ----
    const int crow0 = brow + wm * 64 + (lane >> 4) * 4;
    const int ccol0 = bcol + wn * 64 + (lane & 15);
    float bv[4];
    #pragma unroll
    for (int n = 0; n < 4; ++n) bv[n] = bias[ccol0 + n * 16];
    #pragma unroll
    for (int m = 0; m < 4; ++m) {
        #pragma unroll
        for (int n = 0; n < 4; ++n) {
            #pragma unroll
            for (int j = 0; j < 4; ++j) {
                int row = crow0 + m * 16 + j;
                C[(long)row * OUT_DIM + ccol0 + n * 16] = acc[m][n][j] + bv[n];
            }
        }
    }
}

extern "C" void kernel_launch(void* const* d_in, const int* in_sizes, int n_in,
                              void* d_out, int out_size, void* d_ws, size_t ws_size,
                              hipStream_t stream) {
    const float* x      = (const float*)d_in[0];
    const float* grid   = (const float*)d_in[1];
    const float* coeffs = (const float*)d_in[2];
    const float* alive  = (const float*)d_in[3];
    const float* proj_w = (const float*)d_in[4];
    const float* proj_b = (const float*)d_in[5];
    const float* res_w  = (const float*)d_in[6];
    float* out = (float*)d_out;

    char* w = (char*)d_ws;
    size_t a_bytes = (size_t)M_DIM * KCAT * sizeof(u16);     // 64 MiB
    size_t b_bytes = (size_t)OUT_DIM * KCAT * sizeof(u16);   // 4 MiB
    u16* Abf   = (u16*)w;
    u16* Bw    = (u16*)(w + a_bytes);
    float* pmc = (float*)(w + a_bytes + b_bytes);
    float* pgmin  = pmc + IN_DIM * K_KNOTS;
    float* pscale = pgmin + IN_DIM;

    prep_conv_kernel<<<260, 256, 0, stream>>>(grid, coeffs, alive, proj_w, res_w,
                                              pmc, pgmin, pscale, Bw);
    build_a_kernel<<<(M_DIM / 64) * 4, 512, 0, stream>>>(x, pmc, pgmin, pscale, Abf);
    gemm_kernel<<<(M_DIM / 128) * (OUT_DIM / 256), 512, 0, stream>>>(Abf, Bw, proj_b, out);
}